// Round 10
// baseline (138.711 us; speedup 1.0000x reference)
//
#include <hip/hip_runtime.h>

#define NTOT   131072
#define GCNT   512
#define NGRP   256
#define KMARG  0.02f
#define CMARG  2.0f
#define EPSC   1e-6f

typedef float f4 __attribute__((ext_vector_type(4)));

// Async global->LDS DMA, 16B/lane. LDS dest is wave-uniform base; HW writes
// lane i at base + i*16 (m104/m108). No dest VGPRs -> deep MLP for free.
__device__ __forceinline__ void gld16(const f4* gsrc, f4* ldst) {
  __builtin_amdgcn_global_load_lds(
      (const __attribute__((address_space(1))) void*)gsrc,
      (__attribute__((address_space(3))) void*)ldst, 16, 0, 0);
}

// Multi-value block reduction: reduces M floats across the block (NW wave64s).
template <int NW, int M>
__device__ __forceinline__ void block_sum_m(float* v, float* red) {
  const int t = threadIdx.x;
#pragma unroll
  for (int m = 0; m < M; ++m) {
#pragma unroll
    for (int off = 32; off; off >>= 1) v[m] += __shfl_down(v[m], off, 64);
  }
  __syncthreads();
  if ((t & 63) == 0) {
#pragma unroll
    for (int m = 0; m < M; ++m) red[(t >> 6) * M + m] = v[m];
  }
  __syncthreads();
#pragma unroll
  for (int m = 0; m < M; ++m) {
    float s = 0.0f;
#pragma unroll
    for (int i = 0; i < NW; ++i) s += red[i * M + m];
    v[m] = s;
  }
}

__device__ __forceinline__ float wave_sum(float v) {
#pragma unroll
  for (int off = 32; off; off >>= 1) v += __shfl_down(v, off, 64);
  return v;
}

// One block per group. Phase 1: each wave streams a contiguous 64-row chunk
// (2 zr rows + 2 zv rows per iter = 8 KB) into a PRIVATE double-buffered LDS
// stage via global_load_lds DMA; counted s_waitcnt vmcnt(8) -- loads stay in
// flight across iterations, no barriers in the loop. Phase 2: losses from LDS.
__global__ __launch_bounds__(256) void fused_kernel(const float* __restrict__ zr,
                                                    const float* __restrict__ zv,
                                                    const int* __restrict__ labels,
                                                    const int* __restrict__ varl,
                                                    float* __restrict__ dvec,
                                                    float* __restrict__ gout) {
  __shared__ f4     stg[2][4][4][128];   // [phase][wave][2 zr rows + 2 zv rows][2KB row] = 64 KB
  __shared__ float  red[4 * 4];
  __shared__ float  sd[NGRP];
  __shared__ float2 skv[NGRP];
  __shared__ float  sdat[NGRP];
  const int g = blockIdx.x, t = threadIdx.x;
  const int wave = t >> 6, lane = t & 63;
  const size_t rowbase = (size_t)g * NGRP;
  const size_t wrow0   = rowbase + (size_t)wave * 64;   // this wave's 64-row chunk

  const f4* zr4 = (const f4*)zr;
  const f4* zv4 = (const f4*)zv;

#define STAGE(k, ph) do {                                                  \
    const size_t r0_ = wrow0 + 2 * (size_t)(k);                            \
    const f4* pr_ = zr4 + (r0_ << 7) + lane;                               \
    const f4* pv_ = zv4 + (r0_ << 7) + lane;                               \
    gld16(pr_,       &stg[ph][wave][0][0]);                                \
    gld16(pr_ + 64,  &stg[ph][wave][0][64]);                               \
    gld16(pr_ + 128, &stg[ph][wave][1][0]);                                \
    gld16(pr_ + 192, &stg[ph][wave][1][64]);                               \
    gld16(pv_,       &stg[ph][wave][2][0]);                                \
    gld16(pv_ + 64,  &stg[ph][wave][2][64]);                               \
    gld16(pv_ + 128, &stg[ph][wave][3][0]);                                \
    gld16(pv_ + 192, &stg[ph][wave][3][64]);                               \
  } while (0)

#define CONSUME(k, ph) do {                                                \
    f4 a0_ = stg[ph][wave][0][lane];                                       \
    f4 a1_ = stg[ph][wave][0][lane + 64];                                  \
    f4 c0_ = stg[ph][wave][2][lane];                                       \
    f4 c1_ = stg[ph][wave][2][lane + 64];                                  \
    f4 b0_ = stg[ph][wave][1][lane];                                       \
    f4 b1_ = stg[ph][wave][1][lane + 64];                                  \
    f4 d0_ = stg[ph][wave][3][lane];                                       \
    f4 d1_ = stg[ph][wave][3][lane + 64];                                  \
    f4 p_ = a0_ * c0_ + a1_ * c1_;                                         \
    f4 q_ = b0_ * d0_ + b1_ * d1_;                                         \
    float s0_ = wave_sum((p_.x + p_.y) + (p_.z + p_.w));                   \
    float s1_ = wave_sum((q_.x + q_.y) + (q_.z + q_.w));                   \
    const int rg_ = wave * 64 + 2 * (k);                                   \
    if (lane == 0) {                                                       \
      const float e0_ = 1.0f - s0_, e1_ = 1.0f - s1_;                      \
      sd[rg_]     = e0_;                                                   \
      sd[rg_ + 1] = e1_;                                                   \
      dvec[wrow0 + 2 * (k)]     = e0_;                                     \
      dvec[wrow0 + 2 * (k) + 1] = e1_;                                     \
    }                                                                      \
  } while (0)

  STAGE(0, 0);
#pragma unroll 1
  for (int k = 0; k < 31; ++k) {
    STAGE(k + 1, (k + 1) & 1);                       // 8 more loads in flight
    asm volatile("s_waitcnt vmcnt(8)" ::: "memory"); // stage(k) complete; k+1 still flying
    __builtin_amdgcn_sched_barrier(0);
    CONSUME(k, k & 1);
  }
  asm volatile("s_waitcnt vmcnt(0)" ::: "memory");
  __builtin_amdgcn_sched_barrier(0);
  CONSUME(31, 1);
#undef STAGE
#undef CONSUME
  __syncthreads();

  // ---- Phase 2: group losses (verbatim R3/R9; all LDS/registers) ----
  const int idx = g * NGRP + t;
  const float dv  = sd[t];
  const float vv  = (float)varl[idx];   // var_lens < 10000 -> exact in fp32
  const int   lab = labels[idx];

  skv[t] = make_float2(vv, dv);

  // A: sum d, sum v, label-0 d-sum, label-0 count
  float sA[4] = {dv, vv, (lab == 0) ? dv : 0.0f, (lab == 0) ? 1.0f : 0.0f};
  block_sum_m<4, 4>(sA, red);
  const float sumd = sA[0], sumv = sA[1], sb = sA[2], cb = sA[3];
  const float md = sumd * (1.0f / NGRP), mv = sumv * (1.0f / NGRP);

  // B: central moments (two-pass), corr loss in closed form
  const float vdev = vv - mv, ddev = dv - md;
  float sB[3] = {vdev * vdev, ddev * ddev, vdev * ddev};
  block_sum_m<4, 3>(sB, red);
  const float svv = sB[0], sdd = sB[1], svd = sB[2];
  const float vstd = sqrtf(svv * (1.0f / (NGRP - 1)));
  const float dstd = sqrtf(sdd * (1.0f / (NGRP - 1)));
  const float iv = 1.0f / (vstd + EPSC), id = 1.0f / (dstd + EPSC);
  float corr = (svv * iv * iv + sdd * id * id - 2.0f * svd * iv * id) * (1.0f / NGRP);
  corr = (vstd > 0.0f && dstd > 0.0f) ? corr : 0.0f;

  // C: pairwise rank loss (permutation-invariant) + stable rank for neighbor term
  int rank = 0;
  float pc = 0.0f, ps = 0.0f;
  const float pre = KMARG + dv;
  for (int j = 0; j < NGRP; ++j) {
    const float2 kv = skv[j];          // LDS broadcast
    const float vj = kv.x, dj = kv.y;
    if (vj > vv) {
      pc += 1.0f;
      ps += fmaxf(pre - dj, 0.0f);
    }
    rank += (vj < vv || (vj == vv && j < t)) ? 1 : 0;  // stable rank
  }
  sdat[rank] = dv;                     // scatter into sorted-by-v order
  __syncthreads();
  const float nv = (t < NGRP - 1) ? fmaxf(sdat[t] - sdat[t + 1] + KMARG, 0.0f) : 0.0f;

  float sC[3] = {ps, pc, nv};
  block_sum_m<4, 3>(sC, red);
  const float rank_loss = (sC[1] > 0.0f) ? sC[0] / fmaxf(sC[1], 1.0f) : 0.0f;
  const float neigh = sC[2] * (1.0f / (NGRP - 1));

  if (t == 0) {
    gout[g]            = corr + neigh + rank_loss;
    gout[GCNT + g]     = sb;
    gout[2 * GCNT + g] = cb;
    gout[3 * GCNT + g] = sumd;
  }
}

__global__ __launch_bounds__(512) void final_kernel(const float* __restrict__ gout,
                                                    float* __restrict__ out) {
  __shared__ float red[8 * 4];
  const int t = threadIdx.x;
  float s[4] = {gout[t], gout[GCNT + t], gout[2 * GCNT + t], gout[3 * GCNT + t]};
  block_sum_m<8, 4>(s, red);
  if (t == 0) {
    const float L = s[0], SB = s[1], CB = s[2], SumD = s[3];
    const float SP = SumD - SB;
    const float CP = (float)NTOT - CB;
    const float db = SB / fmaxf(CB, 1.0f);
    const float dp = SP / fmaxf(CP, 1.0f);
    const float l_cdd = (CB > 0.0f && CP > 0.0f) ? fmaxf(CMARG + db - dp, 0.0f) : 0.0f;
    const float l_pcc = L * (1.0f / GCNT);
    out[0] = l_cdd + l_pcc;   // LAMBDA_CD = 0
    out[1] = l_cdd;
    out[2] = l_pcc;
  }
}

extern "C" void kernel_launch(void* const* d_in, const int* in_sizes, int n_in,
                              void* d_out, int out_size, void* d_ws, size_t ws_size,
                              hipStream_t stream) {
  const float* zr     = (const float*)d_in[0];
  const float* zv     = (const float*)d_in[1];
  const int*   labels = (const int*)d_in[2];
  // d_in[3] = groups: contiguous equal-size -> derivable, unused
  const int*   varl   = (const int*)d_in[4];
  float* out  = (float*)d_out;
  float* dvec = out + 3;          // out[3..] = d (N floats)
  float* gws  = (float*)d_ws;     // G*4 floats of group partials

  fused_kernel<<<GCNT, 256, 0, stream>>>(zr, zv, labels, varl, dvec, gws);
  final_kernel<<<1, 512, 0, stream>>>(gws, out);
}

// Round 11
// 112.541 us; speedup vs baseline: 1.2325x; 1.2325x over previous
//
#include <hip/hip_runtime.h>

#define NTOT   131072
#define GCNT   512
#define NGRP   256
#define KMARG  0.02f
#define CMARG  2.0f
#define EPSC   1e-6f

typedef float f4 __attribute__((ext_vector_type(4)));

// Multi-value block reduction: reduces M floats across the block (NW wave64s).
template <int NW, int M>
__device__ __forceinline__ void block_sum_m(float* v, float* red) {
  const int t = threadIdx.x;
#pragma unroll
  for (int m = 0; m < M; ++m) {
#pragma unroll
    for (int off = 32; off; off >>= 1) v[m] += __shfl_down(v[m], off, 64);
  }
  __syncthreads();
  if ((t & 63) == 0) {
#pragma unroll
    for (int m = 0; m < M; ++m) red[(t >> 6) * M + m] = v[m];
  }
  __syncthreads();
#pragma unroll
  for (int m = 0; m < M; ++m) {
    float s = 0.0f;
#pragma unroll
    for (int i = 0; i < NW; ++i) s += red[i * M + m];
    v[m] = s;
  }
}

__device__ __forceinline__ float wave_sum(float v) {
#pragma unroll
  for (int off = 32; off; off >>= 1) v += __shfl_down(v, off, 64);
  return v;
}

// R9 (112.7 us champion) + ONE change: XCD-aware bijective block swizzle (T1).
// Default dispatch round-robins blocks across 8 XCDs, so each XCD walks a
// strided scatter of 1 MB slabs. Swizzled, XCD x owns groups [x*64, (x+1)*64)
// = one contiguous 64 MB span of each stream -> fewer interleaved stream
// contexts per DRAM channel/bank, better page locality on the read path.
__global__ __launch_bounds__(256) void fused_kernel(const float* __restrict__ zr,
                                                    const float* __restrict__ zv,
                                                    const int* __restrict__ labels,
                                                    const int* __restrict__ varl,
                                                    float* __restrict__ dvec,
                                                    float* __restrict__ gout) {
  __shared__ float  red[4 * 4];
  __shared__ float  sd[NGRP];
  __shared__ float2 skv[NGRP];
  __shared__ float  sdat[NGRP];
  // Bijective XCD swizzle: GCNT % 8 == 0, chunk = 64 groups per XCD.
  const int g = (blockIdx.x & 7) * (GCNT / 8) + (blockIdx.x >> 3);
  const int t = threadIdx.x;
  const int wave = t >> 6, lane = t & 63;

  // ---- Phase 1: dots. Each wave: 2 rows/iter, 8 rows/block/iter, 32 iters ----
  const size_t rowbase = (size_t)g * NGRP;
#pragma unroll 2
  for (int it = 0; it < NGRP / 8; ++it) {
    const int rg = it * 8 + wave * 2;            // row within group (2 rows)
    const size_t row0 = rowbase + rg;
    const f4* r = (const f4*)zr + (row0 << 7);   // 128 f4 per row
    const f4* v = (const f4*)zv + (row0 << 7);
    f4 a0 = __builtin_nontemporal_load(r + lane);        // zr: NT (HBM stream)
    f4 b0 = v[lane];                                     // zv: cacheable (L3)
    f4 a1 = __builtin_nontemporal_load(r + lane + 64);
    f4 b1 = v[lane + 64];
    f4 a2 = __builtin_nontemporal_load(r + lane + 128);
    f4 b2 = v[lane + 128];
    f4 a3 = __builtin_nontemporal_load(r + lane + 192);
    f4 b3 = v[lane + 192];
    f4 p = a0 * b0 + a1 * b1;
    f4 q = a2 * b2 + a3 * b3;
    float s0 = wave_sum(p.x + p.y + p.z + p.w);
    float s1 = wave_sum(q.x + q.y + q.z + q.w);
    if (lane == 0) {
      const float d0 = 1.0f - s0, d1 = 1.0f - s1;
      sd[rg]     = d0;
      sd[rg + 1] = d1;
      dvec[row0]     = d0;
      dvec[row0 + 1] = d1;
    }
  }
  __syncthreads();

  // ---- Phase 2: group losses (all from LDS/registers; verbatim R3/R9) ----
  const int idx = g * NGRP + t;
  const float dv  = sd[t];
  const float vv  = (float)varl[idx];   // var_lens < 10000 -> exact in fp32
  const int   lab = labels[idx];

  skv[t] = make_float2(vv, dv);

  // A: sum d, sum v, label-0 d-sum, label-0 count
  float sA[4] = {dv, vv, (lab == 0) ? dv : 0.0f, (lab == 0) ? 1.0f : 0.0f};
  block_sum_m<4, 4>(sA, red);
  const float sumd = sA[0], sumv = sA[1], sb = sA[2], cb = sA[3];
  const float md = sumd * (1.0f / NGRP), mv = sumv * (1.0f / NGRP);

  // B: central moments (two-pass), corr loss in closed form
  const float vdev = vv - mv, ddev = dv - md;
  float sB[3] = {vdev * vdev, ddev * ddev, vdev * ddev};
  block_sum_m<4, 3>(sB, red);
  const float svv = sB[0], sdd = sB[1], svd = sB[2];
  const float vstd = sqrtf(svv * (1.0f / (NGRP - 1)));
  const float dstd = sqrtf(sdd * (1.0f / (NGRP - 1)));
  const float iv = 1.0f / (vstd + EPSC), id = 1.0f / (dstd + EPSC);
  float corr = (svv * iv * iv + sdd * id * id - 2.0f * svd * iv * id) * (1.0f / NGRP);
  corr = (vstd > 0.0f && dstd > 0.0f) ? corr : 0.0f;

  // C: pairwise rank loss (permutation-invariant) + stable rank for neighbor term
  int rank = 0;
  float pc = 0.0f, ps = 0.0f;
  const float pre = KMARG + dv;
  for (int j = 0; j < NGRP; ++j) {
    const float2 kv = skv[j];          // LDS broadcast
    const float vj = kv.x, dj = kv.y;
    if (vj > vv) {
      pc += 1.0f;
      ps += fmaxf(pre - dj, 0.0f);
    }
    rank += (vj < vv || (vj == vv && j < t)) ? 1 : 0;  // stable rank
  }
  sdat[rank] = dv;                     // scatter into sorted-by-v order
  __syncthreads();
  const float nv = (t < NGRP - 1) ? fmaxf(sdat[t] - sdat[t + 1] + KMARG, 0.0f) : 0.0f;

  float sC[3] = {ps, pc, nv};
  block_sum_m<4, 3>(sC, red);
  const float rank_loss = (sC[1] > 0.0f) ? sC[0] / fmaxf(sC[1], 1.0f) : 0.0f;
  const float neigh = sC[2] * (1.0f / (NGRP - 1));

  if (t == 0) {
    gout[g]            = corr + neigh + rank_loss;
    gout[GCNT + g]     = sb;
    gout[2 * GCNT + g] = cb;
    gout[3 * GCNT + g] = sumd;
  }
}

__global__ __launch_bounds__(512) void final_kernel(const float* __restrict__ gout,
                                                    float* __restrict__ out) {
  __shared__ float red[8 * 4];
  const int t = threadIdx.x;
  float s[4] = {gout[t], gout[GCNT + t], gout[2 * GCNT + t], gout[3 * GCNT + t]};
  block_sum_m<8, 4>(s, red);
  if (t == 0) {
    const float L = s[0], SB = s[1], CB = s[2], SumD = s[3];
    const float SP = SumD - SB;
    const float CP = (float)NTOT - CB;
    const float db = SB / fmaxf(CB, 1.0f);
    const float dp = SP / fmaxf(CP, 1.0f);
    const float l_cdd = (CB > 0.0f && CP > 0.0f) ? fmaxf(CMARG + db - dp, 0.0f) : 0.0f;
    const float l_pcc = L * (1.0f / GCNT);
    out[0] = l_cdd + l_pcc;   // LAMBDA_CD = 0
    out[1] = l_cdd;
    out[2] = l_pcc;
  }
}

extern "C" void kernel_launch(void* const* d_in, const int* in_sizes, int n_in,
                              void* d_out, int out_size, void* d_ws, size_t ws_size,
                              hipStream_t stream) {
  const float* zr     = (const float*)d_in[0];
  const float* zv     = (const float*)d_in[1];
  const int*   labels = (const int*)d_in[2];
  // d_in[3] = groups: contiguous equal-size -> derivable, unused
  const int*   varl   = (const int*)d_in[4];
  float* out  = (float*)d_out;
  float* dvec = out + 3;          // out[3..] = d (N floats)
  float* gws  = (float*)d_ws;     // G*4 floats of group partials

  fused_kernel<<<GCNT, 256, 0, stream>>>(zr, zv, labels, varl, dvec, gws);
  final_kernel<<<1, 512, 0, stream>>>(gws, out);
}